// Round 8
// baseline (367.794 us; speedup 1.0000x reference)
//
#include <hip/hip_runtime.h>
#include <hip/hip_bf16.h>
#include <stdint.h>
#include <stddef.h>

// Problem constants (fixed by the reference)
#define B_DIM 4
#define NH    16
#define LSEQ  2048
#define HD    64
#define DM    1024
#define TOKENS (B_DIM * LSEQ)   // 8192

typedef __bf16 bf16_t;
typedef __attribute__((ext_vector_type(8))) __bf16 bf16x8;
typedef __attribute__((ext_vector_type(4))) __bf16 bf16x4;
typedef __attribute__((ext_vector_type(4))) float  f32x4;

// async global->LDS, 16B per lane, lane i lands at ldsbase + i*16
#define GLD16(gp, lp) \
  __builtin_amdgcn_global_load_lds((__attribute__((address_space(1))) void*)(gp), \
                                   (__attribute__((address_space(3))) void*)(lp), 16, 0, 0)

// raw sync primitives (T4: counted vmcnt; single per-K-tile drain with ~6
// phases of cover — never a freshly-issued drain)
#define WAITV6 asm volatile("s_waitcnt vmcnt(6)" ::: "memory")
#define WAITV4 asm volatile("s_waitcnt vmcnt(4)" ::: "memory")
#define WAITV0 asm volatile("s_waitcnt vmcnt(0)" ::: "memory")
#define WAITL0 asm volatile("s_waitcnt lgkmcnt(0)" ::: "memory")
#define SBAR   __builtin_amdgcn_s_barrier()
#define SCHED0 __builtin_amdgcn_sched_barrier(0)

__device__ __forceinline__ f32x4 mfma_16x16x32(bf16x8 a, bf16x8 b, f32x4 c) {
  return __builtin_amdgcn_mfma_f32_16x16x32_bf16(a, b, c, 0, 0, 0);
}

// ---------------------------------------------------------------------------
// Fused prep kernel (ONE dispatch): 1D grid decode.
//  [0, 24576)       : 3 activation casts f32->bf16 (q,k,v -> xq,xk,xv)
//  [24576, 28672)   : 4 weight casts f32->bf16 (Wq,Wk,Wv,Wo)
//  [28672, 29696)   : 2 interleaved (cos,sin) float2 tables (q,k) in d_out
// ---------------------------------------------------------------------------
__global__ __launch_bounds__(256) void prep_kernel(const float* __restrict__ q,
                                                   const float* __restrict__ k,
                                                   const float* __restrict__ v,
                                                   const float* __restrict__ Wq,
                                                   const float* __restrict__ Wk,
                                                   const float* __restrict__ Wv,
                                                   const float* __restrict__ Wo,
                                                   const float* __restrict__ cos_q,
                                                   const float* __restrict__ sin_q,
                                                   const float* __restrict__ cos_k,
                                                   const float* __restrict__ sin_k,
                                                   bf16_t* __restrict__ xdst,
                                                   bf16_t* __restrict__ wdst,
                                                   float2* __restrict__ cs) {
  const int bid = blockIdx.x;
  const int tid = threadIdx.x;
  if (bid < 24576) {                      // activation casts, n = TOKENS*DM
    const int s = bid >> 13, off = bid & 8191;
    const float* src = (s == 0) ? q : (s == 1) ? k : v;
    const int i = (off * 256 + tid) * 4;
    const float4 val = *(const float4*)(src + i);
    bf16x4 o;
    o[0] = (bf16_t)val.x; o[1] = (bf16_t)val.y; o[2] = (bf16_t)val.z; o[3] = (bf16_t)val.w;
    *(bf16x4*)(xdst + (size_t)s * (TOKENS * (size_t)DM) + i) = o;
  } else if (bid < 28672) {               // weight casts, n = DM*DM
    const int s = (bid - 24576) >> 10, off = (bid - 24576) & 1023;
    const float* src = (s == 0) ? Wq : (s == 1) ? Wk : (s == 2) ? Wv : Wo;
    const int i = (off * 256 + tid) * 4;
    const float4 val = *(const float4*)(src + i);
    bf16x4 o;
    o[0] = (bf16_t)val.x; o[1] = (bf16_t)val.y; o[2] = (bf16_t)val.z; o[3] = (bf16_t)val.w;
    *(bf16x4*)(wdst + (size_t)s * (DM * (size_t)DM) + i) = o;
  } else {                                // cs tables, n = TOKENS*HD = 524288
    const int s = (bid - 28672) >> 9, off = (bid - 28672) & 511;
    const float* cp = (s == 0) ? cos_q : cos_k;
    const float* sp = (s == 0) ? sin_q : sin_k;
    const int i = (off * 256 + tid) * 4;
    const float4 c4 = *(const float4*)(cp + i);
    const float4 s4 = *(const float4*)(sp + i);
    float2* d = cs + (size_t)s * (TOKENS * (size_t)HD) + i;
    d[0] = make_float2(c4.x, s4.x);
    d[1] = make_float2(c4.y, s4.y);
    d[2] = make_float2(c4.z, s4.z);
    d[3] = make_float2(c4.w, s4.w);
  }
}

// ---------------------------------------------------------------------------
// Round-8 GEMM: 8-PHASE schedule (T3+T4+T5), the only measured escape from
// the 2-phase ~600 TF ceiling (m233; r4-r7 all plateaued there; regime-gate:
// setprio/swizzle only pay at 8-phase).
// Geometry: BM=256 BN=128 BK=64, 512 thr / 8 waves (4M x 2N), wave 64x64,
// LDS 96KB 2-buf. Per K-tile: 8 phases (ksub,i): {ds_read af (+4 bfr at i==0)
// || 1 staging round for tile t+1 (phases 0-5) -> s_barrier -> lgkmcnt(0) ->
// setprio(1) 4xMFMA setprio(0) -> s_barrier}. ONE per-wave vmcnt(0) per
// K-tile at the boundary, 6-phase lead. kk order per acc element unchanged
// (32-ascending) -> bit-identical output.
// LDS swizzle: col-block (of 8) XOR row&7; source-side pre-swizzle (T21),
// stage row&7 == lane>>3, read row&7 == l16&7 — conflict-free.
// ---------------------------------------------------------------------------
#define STAGE_ROUND(DBUF, KK2, R)                                             \
  if ((R) < 4) {                                                              \
    GLD16(Ag0 + (size_t)(R) * 64 * DM + (KK2),                                \
          Asb[DBUF] + ((R) * 64 + wave * 8) * 64);                            \
  } else {                                                                    \
    GLD16(Bg0 + (size_t)((R) - 4) * 64 * DM + (KK2),                          \
          Bsb[DBUF] + (((R) - 4) * 64 + wave * 8) * 64);                      \
  }

#define KPH(CUR, KS, I, STG, KK2, R)                                          \
  {                                                                           \
    const bf16x8 af_ = *(const bf16x8*)(Asb[CUR] + (wm + (I) * 16 + l16) * 64 \
                                        + ((((KS) << 2) + quad) ^ sw8) * 8);  \
    if ((I) == 0) {                                                           \
      bfr[0] = *(const bf16x8*)(Bsb[CUR] + (wn + 0 + l16) * 64 + ((((KS) << 2) + quad) ^ sw8) * 8);  \
      bfr[1] = *(const bf16x8*)(Bsb[CUR] + (wn + 16 + l16) * 64 + ((((KS) << 2) + quad) ^ sw8) * 8); \
      bfr[2] = *(const bf16x8*)(Bsb[CUR] + (wn + 32 + l16) * 64 + ((((KS) << 2) + quad) ^ sw8) * 8); \
      bfr[3] = *(const bf16x8*)(Bsb[CUR] + (wn + 48 + l16) * 64 + ((((KS) << 2) + quad) ^ sw8) * 8); \
    }                                                                         \
    if (STG) { STAGE_ROUND((CUR) ^ 1, KK2, R) }                               \
    SBAR; WAITL0; SCHED0;                                                     \
    __builtin_amdgcn_s_setprio(1);                                            \
    acc[I][0] = mfma_16x16x32(af_, bfr[0], acc[I][0]);                        \
    acc[I][1] = mfma_16x16x32(af_, bfr[1], acc[I][1]);                        \
    acc[I][2] = mfma_16x16x32(af_, bfr[2], acc[I][2]);                        \
    acc[I][3] = mfma_16x16x32(af_, bfr[3], acc[I][3]);                        \
    __builtin_amdgcn_s_setprio(0);                                            \
  }

#define KTILE(CUR, KK, STG)                                                   \
  {                                                                           \
    bf16x8 bfr[4];                                                            \
    KPH(CUR, 0, 0, STG, (KK) + 64, 0) SBAR;                                   \
    KPH(CUR, 0, 1, STG, (KK) + 64, 1) SBAR;                                   \
    KPH(CUR, 0, 2, STG, (KK) + 64, 2) SBAR;                                   \
    KPH(CUR, 0, 3, STG, (KK) + 64, 3) SBAR;                                   \
    KPH(CUR, 1, 0, STG, (KK) + 64, 4) SBAR;                                   \
    KPH(CUR, 1, 1, STG, (KK) + 64, 5) SBAR;                                   \
    KPH(CUR, 1, 2, false, 0, 0) SBAR;                                         \
    KPH(CUR, 1, 3, false, 0, 0)                                               \
  }

#define GEMM8_SETUP(APTR, BPTR)                                               \
  const int wave = tid >> 6, lane = tid & 63;                                 \
  const int quad = lane >> 4, l16 = lane & 15;                                \
  const int wm = (wave >> 1) * 64, wn = (wave & 1) * 64;                      \
  const int sw8 = l16 & 7;                                                    \
  const int srow8 = lane >> 3;                                                \
  const int sblk = ((lane & 7) ^ srow8) * 8;                                  \
  const bf16_t* Ag0 = (APTR) + (size_t)(m0 + wave * 8 + srow8) * DM + sblk;   \
  const bf16_t* Bg0 = (BPTR) + (size_t)(n0 + wave * 8 + srow8) * DM + sblk;   \
  bf16_t* const Asb[2] = {&As[0][0], &As[1][0]};                              \
  bf16_t* const Bsb[2] = {&Bs[0][0], &Bs[1][0]};

// 16 K-tiles of 64. Prologue stages tiles 0,1 (12 loads; vmcnt(6) = tile 0's
// done). In-loop: tile t stages t+1 (6 rounds, phases 0-5); boundary
// WAITV0+SBAR (per-wave drain of loads issued ~6 phases earlier).
#define GEMM8_LOOP                                                            \
  STAGE_ROUND(0, 0, 0) STAGE_ROUND(0, 0, 1) STAGE_ROUND(0, 0, 2)              \
  STAGE_ROUND(0, 0, 3) STAGE_ROUND(0, 0, 4) STAGE_ROUND(0, 0, 5)              \
  STAGE_ROUND(1, 64, 0) STAGE_ROUND(1, 64, 1) STAGE_ROUND(1, 64, 2)           \
  STAGE_ROUND(1, 64, 3) STAGE_ROUND(1, 64, 4) STAGE_ROUND(1, 64, 5)           \
  WAITV6; SBAR;                                                               \
  KTILE(0, 0, false) WAITV0; SBAR;                                            \
  for (int tt = 0; tt < 7; ++tt) {                                            \
    const int kk1 = tt * 128 + 64;                                            \
    KTILE(1, kk1, true) WAITV0; SBAR;                                         \
    KTILE(0, kk1 + 64, true) WAITV0; SBAR;                                    \
  }                                                                           \
  KTILE(1, 960, false)

// ---------------------------------------------------------------------------
// Fused QKV projection: ONE dispatch, blockIdx.z in {0,1,2} = q,k,v.
// 256x128-tile 8-phase bf16 GEMM. Grid (32, 8, 3) = 768 blocks = 3 exact
// generations at 1 block/CU (96KB LDS).
// ---------------------------------------------------------------------------
__global__ __launch_bounds__(512, 2) void qkv_proj_kernel(const bf16_t* __restrict__ X,
                                                          const bf16_t* __restrict__ Wb,
                                                          const float* __restrict__ bq,
                                                          const float* __restrict__ bk,
                                                          const float* __restrict__ bv,
                                                          const float2* __restrict__ csq,
                                                          const float2* __restrict__ csk,
                                                          bf16_t* __restrict__ qtb,
                                                          bf16_t* __restrict__ ktb,
                                                          bf16_t* __restrict__ vtb) {
  __shared__ bf16_t As[2][256 * 64];
  __shared__ bf16_t Bs[2][128 * 64];
  const int z = blockIdx.z;
  const bf16_t* A  = X  + (size_t)z * TOKENS * DM;
  const bf16_t* Bw = Wb + (size_t)z * DM * DM;
  const float* bias = (z == 0) ? bq : (z == 1) ? bk : bv;

  const int tid = threadIdx.x;
  const int m0 = blockIdx.x * 256, n0 = blockIdx.y * 128;

  f32x4 acc[4][4];
#pragma unroll
  for (int i = 0; i < 4; ++i)
#pragma unroll
    for (int j = 0; j < 4; ++j) acc[i][j] = (f32x4){0.f, 0.f, 0.f, 0.f};

  GEMM8_SETUP(A, Bw)

  GEMM8_LOOP

  // epilogue: C row = quad*4+reg, col = l16 (m89-verified C/D layout)
  // wave n-span = 64 = exactly one head (wn multiple of 64)
  if (z < 2) {
    const float2* cst = (z == 0) ? csq : csk;
    bf16_t* out = (z == 0) ? qtb : ktb;
    const int h = (n0 + wn) >> 6;
#pragma unroll
    for (int i = 0; i < 4; ++i) {
#pragma unroll
      for (int j = 0; j < 2; ++j) {
        const int hd1 = j * 16 + l16;
        const int hd2 = hd1 + 32;
        const float bn1 = bias[n0 + wn + hd1];
        const float bn2 = bias[n0 + wn + hd2];
#pragma unroll
        for (int r = 0; r < 4; ++r) {
          const int m = m0 + wm + i * 16 + quad * 4 + r;
          const int b = m >> 11, l = m & (LSEQ - 1);
          const size_t cb = ((size_t)b * LSEQ + l) * HD;
          // explicit bf16 round BEFORE rope (verified numerics)
          const float x1 = (float)(bf16_t)(acc[i][j][r] + bn1);
          const float x2 = (float)(bf16_t)(acc[i][j + 2][r] + bn2);
          const float2 cs1 = cst[cb + hd1];
          const float2 cs2 = cst[cb + hd2];
          bf16_t* dst = out + (((size_t)(b * NH + h)) * LSEQ + l) * HD;
          dst[hd1] = (bf16_t)(x1 * cs1.x - x2 * cs1.y);
          dst[hd2] = (bf16_t)(x2 * cs2.x + x1 * cs2.y);
        }
      }
    }
  } else {
#pragma unroll
    for (int i = 0; i < 4; ++i) {
      const int mb = m0 + wm + i * 16 + quad * 4;
      const int b = mb >> 11, l = mb & (LSEQ - 1);
#pragma unroll
      for (int j = 0; j < 4; ++j) {
        const int n = n0 + wn + j * 16 + l16;
        const int h = n >> 6, hd = n & (HD - 1);
        const float bn = bias[n];
        bf16x4 pk;
#pragma unroll
        for (int r = 0; r < 4; ++r) pk[r] = (bf16_t)(acc[i][j][r] + bn);
        *(bf16x4*)(vtb + (((size_t)(b * NH + h)) * HD + hd) * LSEQ + l) = pk;
      }
    }
  }
}

// ---------------------------------------------------------------------------
// Out projection: C = A * Wo^T + bo, f32 store. 8-phase, grid (32,8) = 256
// blocks = exactly 1 generation.
// ---------------------------------------------------------------------------
__global__ __launch_bounds__(512, 2) void out_gemm_kernel(const bf16_t* __restrict__ A,
                                                          const bf16_t* __restrict__ Bw,
                                                          const float* __restrict__ bias,
                                                          float* __restrict__ out) {
  __shared__ bf16_t As[2][256 * 64];
  __shared__ bf16_t Bs[2][128 * 64];
  const int tid = threadIdx.x;
  const int m0 = blockIdx.x * 256, n0 = blockIdx.y * 128;

  f32x4 acc[4][4];
#pragma unroll
  for (int i = 0; i < 4; ++i)
#pragma unroll
    for (int j = 0; j < 4; ++j) acc[i][j] = (f32x4){0.f, 0.f, 0.f, 0.f};

  GEMM8_SETUP(A, Bw)

  GEMM8_LOOP

#pragma unroll
  for (int i = 0; i < 4; ++i)
#pragma unroll
    for (int j = 0; j < 4; ++j) {
      const int n  = n0 + wn + j * 16 + l16;
      const float bn = bias[n];
#pragma unroll
      for (int r = 0; r < 4; ++r) {
        const int m = m0 + wm + i * 16 + quad * 4 + r;
        out[(size_t)m * DM + n] = acc[i][j][r] + bn;
      }
    }
}

// ---------------------------------------------------------------------------
// Flash attention v7 (unchanged): T4 counted-vmcnt 2-deep, XCD remap,
// sigma-permuted K staging, in-register P transpose, XOR swizzle, mask
// pre-scan, l via ones-MFMA.
// ---------------------------------------------------------------------------
#define ATTN_TILE(K0)                                                         \
  {                                                                           \
    const bf16_t* Kc = &Kl[cur][0];                                           \
    const bf16_t* Vc = &Vl[cur][0];                                           \
    f32x4 S[2][4];                                                            \
    _Pragma("unroll") for (int j = 0; j < 4; ++j) {                           \
      const bf16x8 kb0 = *(const bf16x8*)(Kc + oA + j * 1024);                \
      const bf16x8 kb1 = *(const bf16x8*)(Kc + oB + j * 1024);                \
      _Pragma("unroll") for (int u = 0; u < 2; ++u) {                         \
        f32x4 a = (f32x4){0.f, 0.f, 0.f, 0.f};                                \
        a = mfma_16x16x32(kb0, qa[u][0], a);                                  \
        a = mfma_16x16x32(kb1, qa[u][1], a);                                  \
        _Pragma("unroll") for (int r = 0; r < 4; ++r)                         \
          S[u][j][r] = __builtin_amdgcn_exp2f(a[r] * scale_l2e);              \
      }                                                                       \
    }                                                                         \
    if (has_mask) {                                                           \
      const uint64_t mlo = *(const uint64_t*)(mrow + (K0) + quad * 8);        \
      const uint64_t mhi = *(const uint64_t*)(mrow + (K0) + 32 + quad * 8);   \
      if (!__all((mlo | mhi) == 0)) {                                         \
        _Pragma("unroll") for (int j = 0; j < 4; ++j) {                       \
          const uint64_t mm = (j & 2) ? mhi : mlo;                            \
          _Pragma("unroll") for (int r = 0; r < 4; ++r)                       \
            if ((mm >> (((j & 1) * 4 + r) * 8)) & 0xff) {                     \
              S[0][j][r] = 0.f;                                               \
              S[1][j][r] = 0.f;                                               \
            }                                                                 \
        }                                                                     \
      }                                                                       \
    }                                                                         \
    bf16x8 pa[2][2];                                                          \
    _Pragma("unroll") for (int u = 0; u < 2; ++u)                             \
      _Pragma("unroll") for (int f = 0; f < 2; ++f)                           \
        _Pragma("unroll") for (int e = 0; e < 8; ++e)                         \
          pa[u][f][e] = (bf16_t)S[u][2 * f + (e >> 2)][e & 3];                \
    _Pragma("unroll") for (int u = 0; u < 2; ++u) {                           \
      Ol[u] = mfma_16x16x32(pa[u][0], ones, Ol[u]);                           \
      Ol[u] = mfma_16x16x32(pa[u][1], ones, Ol[u]);                           \
    }                                                                         \
    _Pragma("unroll") for (int jd = 0; jd < 4; ++jd) {                        \
      const bf16x8 vb0 = *(const bf16x8*)(Vc + oA + jd * 1024);               \
      const bf16x8 vb1 = *(const bf16x8*)(Vc + oB + jd * 1024);               \
      _Pragma("unroll") for (int u = 0; u < 2; ++u) {                         \
        O[u][jd] = mfma_16x16x32(pa[u][0], vb0, O[u][jd]);                    \
        O[u][jd] = mfma_16x16x32(pa[u][1], vb1, O[u][jd]);                    \
      }                                                                       \
    }                                                                         \
  }

__global__ __launch_bounds__(256, 4) void attn_kernel(const bf16_t* __restrict__ qt,
                                                      const bf16_t* __restrict__ kt,
                                                      const bf16_t* __restrict__ vt,
                                                      const unsigned char* __restrict__ mask,
                                                      bf16_t* __restrict__ ctx) {
  __shared__ bf16_t Kl[2][64 * 64];        // [pos][d], col-blocks swizzled by pos&7
  __shared__ bf16_t Vl[2][64 * 64];        // [d][kk],  col-blocks swizzled by d&7
  __shared__ int mflag;
  // XCD remap: XCD a <- bh in [8a,8a+8), all 16 q-tiles (bijective over 1024)
  const int L  = blockIdx.x + (blockIdx.y << 4);
  const int bh = ((L & 7) << 3) | ((L >> 3) & 7);
  const int q0 = (L >> 6) * 128;
  const int b = bh >> 4, h = bh & (NH - 1);
  const int tid = threadIdx.x;
  const int wave = tid >> 6, lane = tid & 63;
  const int quad = lane >> 4, l16 = lane & 15;
  const float scale_l2e = 0.125f * 1.44269504f;  // HD^-0.5 * log2(e)

  const bf16_t* kbase = kt + (size_t)bh * LSEQ * HD;
  const bf16_t* vbase = vt + (size_t)bh * HD * LSEQ;
  const unsigned char* mrow = mask + (size_t)b * LSEQ;

  if (tid == 0) mflag = 0;
  __syncthreads();
  // mask pre-scan: 256 threads x 8B = entire 2048B row
  {
    const uint64_t mw = ((const uint64_t*)mrow)[tid];
    if (mw != 0) atomicOr(&mflag, 1);
  }

  // Q fragments (m=l16, k=quad*8+e), used as B-operand of swapped QK^T
  bf16x8 qa[2][2];
#pragma unroll
  for (int u = 0; u < 2; ++u) {
    const bf16_t* qrow = qt + (((size_t)bh * LSEQ) + q0 + wave * 32 + u * 16 + l16) * HD;
    qa[u][0] = *(const bf16x8*)(qrow + quad * 8);
    qa[u][1] = *(const bf16x8*)(qrow + 32 + quad * 8);
  }

  f32x4 O[2][4];
  f32x4 Ol[2];
#pragma unroll
  for (int u = 0; u < 2; ++u) {
    Ol[u] = (f32x4){0.f, 0.f, 0.f, 0.f};
#pragma unroll
    for (int j = 0; j < 4; ++j) O[u][j] = (f32x4){0.f, 0.f, 0.f, 0.f};
  }
  bf16x8 ones;
#pragma unroll
  for (int e = 0; e < 8; ++e) ones[e] = (bf16_t)1.0f;

  // --- hoisted per-lane offsets ---
  const int srow8 = lane >> 3;  // 0..7 within 8-row chunk
  const int scb   = lane & 7;   // LDS col-block position
  const int c0 = wave * 2, c1 = c0 + 1;
  const int p0 = c0 * 8 + srow8, p1 = p0 + 8;
  const int g0 = (scb ^ srow8) * 8;   // p&7 == srow8 for both chunks
  const int sig0 = ((p0 >> 5) << 5) | (((p0 >> 2) & 3) << 3) | (((p0 >> 4) & 1) << 2) | (p0 & 3);
  const int sig1 = ((p1 >> 5) << 5) | (((p1 >> 2) & 3) << 3) | (((p1 >> 4) & 1) << 2) | (p1 & 3);
  const int kgo0 = sig0 * HD + g0, kgo1 = sig1 * HD + g0;      // K global lane offsets
  const int vgo0 = p0 * LSEQ + g0, vgo1 = p1 * LSEQ + g0;      // V global lane offsets
  const int ld0 = c0 * 512, ld1 = c1 * 512;                    // LDS dst offsets

  // fragment-read offsets: sw = (j*16+l16)&7 == l16&7 for all j
  const int sw  = l16 & 7;
  const int oA  = l16 * 64 + ((quad ^ sw) << 3);
  const int oB  = l16 * 64 + (((quad + 4) ^ sw) << 3);

  // prologue: stage tiles 0 and 1 (K rows sigma-permuted); 8 loads in flight
  GLD16(kbase + kgo0, &Kl[0][0] + ld0);
  GLD16(kbase + kgo1, &Kl[0][0] + ld1);
  GLD16(vbase + vgo0, &Vl[0][0] + ld0);
  GLD16(vbase + vgo1, &Vl[0][0] + ld1);
  GLD16(kbase + (size_t)64 * HD + kgo0, &Kl[1][0] + ld0);
  GLD16(kbase + (size_t)64 * HD + kgo1, &Kl[1][0] + ld1);
  GLD16(vbase + (size_t)(vgo0 + 64), &Vl[1][0] + ld0);
  GLD16(vbase + (size_t)(vgo1 + 64), &Vl[1][0] + ld1);

  // non-draining mflag sync: own atomic done (lgkm), then barrier, then read
  WAITL0; SBAR;
  const bool has_mask = (mflag != 0);

  int cur = 0;
  for (int t = 0; t < 30; ++t) {
    WAITV4; SBAR; SCHED0;
    ATTN_TILE(t * 64);
    WAITL0; SBAR; SCHED0;
    {
      const int k0n = t * 64 + 128;
      bf16_t* Kd = &Kl[cur][0];
      bf16_t* Vd = &Vl[cur][0];
      GLD16(kbase + (size_t)k0n * HD + kgo0, Kd + ld0);
      GLD16(kbase + (size_t)k0n * HD + kgo1, Kd + ld1);
      GLD16(vbase + (size_t)(vgo0 + k0n), Vd + ld0);
      GLD16(vbase + (size_t)(vgo1 + k0n), Vd + ld1);
    }
    cur ^= 1;
  }
  // t=30: own loads are oldest 4 of 8
  WAITV4; SBAR; SCHED0;
  ATTN_TILE(30 * 64);
  cur ^= 1;
  // t=31: last tile
  WAITV0; SBAR; SCHED0;
  ATTN_TILE(31 * 64);

  // epilogue: normalize and write ctx [B, LSEQ, NH*HD] bf16 (token-major)
#pragma unroll
  for (int u = 0; u < 2; ++u) {
    f32x4 linv;
#pragma unroll
    for (int r = 0; r < 4; ++r) linv[r] = 1.0f / Ol[u][r];
#pragma unroll
    for (int jd = 0; jd < 4; ++jd)
#pragma unroll
      for (int r = 0; r < 4; ++r) {
        const int l = q0 + wave * 32 + u * 16 + quad * 4 + r;
        const int d = h * HD + jd * 16 + l16;
        const float o = O[u][jd][r] * linv[r];
        ctx[((size_t)b * LSEQ + l) * DM + d] = (bf16_t)o;
      }
  }
}

// ---------------------------------------------------------------------------
extern "C" void kernel_launch(void* const* d_in, const int* in_sizes, int n_in,
                              void* d_out, int out_size, void* d_ws, size_t ws_size,
                              hipStream_t stream) {
  (void)in_sizes; (void)n_in; (void)out_size; (void)ws_size;
  const float* query = (const float*)d_in[0];
  const float* key   = (const float*)d_in[1];
  const float* value = (const float*)d_in[2];
  const float* cos_q = (const float*)d_in[3];
  const float* sin_q = (const float*)d_in[4];
  const float* cos_k = (const float*)d_in[5];
  const float* sin_k = (const float*)d_in[6];
  const unsigned char* mask = (const unsigned char*)d_in[7];
  const float* Wq = (const float*)d_in[8];
  const float* bq = (const float*)d_in[9];
  const float* Wk = (const float*)d_in[10];
  const float* bk = (const float*)d_in[11];
  const float* Wv = (const float*)d_in[12];
  const float* bv = (const float*)d_in[13];
  const float* Wo = (const float*)d_in[14];
  const float* bo = (const float*)d_in[15];
  float* out = (float*)d_out;

  const size_t ACT = (size_t)TOKENS * DM;  // 8388608
  const size_t WEL = (size_t)DM * DM;      // 1048576
  const size_t CSN = (size_t)TOKENS * HD;  // 524288 float2 per table

  bf16_t* p   = (bf16_t*)d_ws;
  bf16_t* xq  = p; p += ACT;    // xq,xk,xv contiguous (prep dst / qkv A base)
  bf16_t* xk  = p; p += ACT;
  bf16_t* xv  = p; p += ACT;
  bf16_t* wqb = p; p += WEL;    // wqb..wob contiguous (prep dst / qkv W base)
  bf16_t* wkb = p; p += WEL;
  bf16_t* wvb = p; p += WEL;
  bf16_t* wob = p; p += WEL;
  bf16_t* qtb = p; p += ACT;
  bf16_t* ktb = p; p += ACT;
  bf16_t* vtb = p; p += ACT;
  bf16_t* ctx = xk;  // alias: xk dead after qkv proj
  (void)xv; (void)wkb; (void)wvb;

  // cos/sin float2 tables live in d_out (32MB f32): only out_gemm writes
  // d_out, at the very end — free scratch until then.
  float2* csq = (float2*)out;        // 4MB
  float2* csk = csq + CSN;           // 4MB

  // fused prep: casts + cs-table build, ONE dispatch
  prep_kernel<<<dim3(29696), 256, 0, stream>>>(query, key, value, Wq, Wk, Wv, Wo,
                                               cos_q, sin_q, cos_k, sin_k,
                                               xq, wqb, csq);

  // fused q/k/v projections (one dispatch, z = which projection)
  qkv_proj_kernel<<<dim3(TOKENS / 256, DM / 128, 3), 512, 0, stream>>>(
      xq, wqb, bq, bk, bv, csq, csk, qtb, ktb, vtb);

  // flash attention -> ctx [B, LSEQ, DM] bf16
  attn_kernel<<<dim3(LSEQ / 128, B_DIM * NH), 256, 0, stream>>>(qtb, ktb, vtb, mask, ctx);

  // output projection -> f32 d_out (overwrites the cs scratch)
  out_gemm_kernel<<<dim3(TOKENS / 256, DM / 128), 512, 0, stream>>>(ctx, wob, bo, out);
}

// Round 9
// 341.561 us; speedup vs baseline: 1.0768x; 1.0768x over previous
//
#include <hip/hip_runtime.h>
#include <hip/hip_bf16.h>
#include <stdint.h>
#include <stddef.h>

// Problem constants (fixed by the reference)
#define B_DIM 4
#define NH    16
#define LSEQ  2048
#define HD    64
#define DM    1024
#define TOKENS (B_DIM * LSEQ)   // 8192

typedef __bf16 bf16_t;
typedef __attribute__((ext_vector_type(8))) __bf16 bf16x8;
typedef __attribute__((ext_vector_type(4))) __bf16 bf16x4;
typedef __attribute__((ext_vector_type(4))) float  f32x4;

// async global->LDS, 16B per lane, lane i lands at ldsbase + i*16
#define GLD16(gp, lp) \
  __builtin_amdgcn_global_load_lds((__attribute__((address_space(1))) void*)(gp), \
                                   (__attribute__((address_space(3))) void*)(lp), 16, 0, 0)

// raw sync primitives (T4: counted vmcnt, NEVER vmcnt(0) drain in main loop)
#define WAITV4 asm volatile("s_waitcnt vmcnt(4)" ::: "memory")
#define WAITV2 asm volatile("s_waitcnt vmcnt(2)" ::: "memory")
#define WAITV0 asm volatile("s_waitcnt vmcnt(0)" ::: "memory")
#define WAITL0 asm volatile("s_waitcnt lgkmcnt(0)" ::: "memory")
#define SBAR   __builtin_amdgcn_s_barrier()
#define SCHED0 __builtin_amdgcn_sched_barrier(0)

__device__ __forceinline__ f32x4 mfma_16x16x32(bf16x8 a, bf16x8 b, f32x4 c) {
  return __builtin_amdgcn_mfma_f32_16x16x32_bf16(a, b, c, 0, 0, 0);
}

// ---------------------------------------------------------------------------
// Fused prep kernel (ONE dispatch, r6-proven): 1D grid decode.
//  [0, 24576)       : 3 activation casts f32->bf16 (q,k,v -> xq,xk,xv)
//  [24576, 28672)   : 4 weight casts f32->bf16 (Wq,Wk,Wv,Wo)
//  [28672, 29696)   : 2 interleaved (cos,sin) float2 tables (q,k) in d_out
// ---------------------------------------------------------------------------
__global__ __launch_bounds__(256) void prep_kernel(const float* __restrict__ q,
                                                   const float* __restrict__ k,
                                                   const float* __restrict__ v,
                                                   const float* __restrict__ Wq,
                                                   const float* __restrict__ Wk,
                                                   const float* __restrict__ Wv,
                                                   const float* __restrict__ Wo,
                                                   const float* __restrict__ cos_q,
                                                   const float* __restrict__ sin_q,
                                                   const float* __restrict__ cos_k,
                                                   const float* __restrict__ sin_k,
                                                   bf16_t* __restrict__ xdst,
                                                   bf16_t* __restrict__ wdst,
                                                   float2* __restrict__ cs) {
  const int bid = blockIdx.x;
  const int tid = threadIdx.x;
  if (bid < 24576) {                      // activation casts, n = TOKENS*DM
    const int s = bid >> 13, off = bid & 8191;
    const float* src = (s == 0) ? q : (s == 1) ? k : v;
    const int i = (off * 256 + tid) * 4;
    const float4 val = *(const float4*)(src + i);
    bf16x4 o;
    o[0] = (bf16_t)val.x; o[1] = (bf16_t)val.y; o[2] = (bf16_t)val.z; o[3] = (bf16_t)val.w;
    *(bf16x4*)(xdst + (size_t)s * (TOKENS * (size_t)DM) + i) = o;
  } else if (bid < 28672) {               // weight casts, n = DM*DM
    const int s = (bid - 24576) >> 10, off = (bid - 24576) & 1023;
    const float* src = (s == 0) ? Wq : (s == 1) ? Wk : (s == 2) ? Wv : Wo;
    const int i = (off * 256 + tid) * 4;
    const float4 val = *(const float4*)(src + i);
    bf16x4 o;
    o[0] = (bf16_t)val.x; o[1] = (bf16_t)val.y; o[2] = (bf16_t)val.z; o[3] = (bf16_t)val.w;
    *(bf16x4*)(wdst + (size_t)s * (DM * (size_t)DM) + i) = o;
  } else {                                // cs tables, n = TOKENS*HD = 524288
    const int s = (bid - 28672) >> 9, off = (bid - 28672) & 511;
    const float* cp = (s == 0) ? cos_q : cos_k;
    const float* sp = (s == 0) ? sin_q : sin_k;
    const int i = (off * 256 + tid) * 4;
    const float4 c4 = *(const float4*)(cp + i);
    const float4 s4 = *(const float4*)(sp + i);
    float2* d = cs + (size_t)s * (TOKENS * (size_t)HD) + i;
    d[0] = make_float2(c4.x, s4.x);
    d[1] = make_float2(c4.y, s4.y);
    d[2] = make_float2(c4.z, s4.z);
    d[3] = make_float2(c4.w, s4.w);
  }
}

// GEMM tile body (r6-proven config, RESTORED after r7/r8 regressions):
// 128x128 tile, 2-deep counted-vmcnt pipeline. This tile's 4 loads are the
// OLDEST outstanding -> vmcnt(4); prefetch of tile i+2 issued AFTER the
// read-done barrier, full iteration to land. 8-phase (r8) and fat-tile (r7)
// both measured worse; 2-phase ~600 TF is this structure's ceiling (m233).
#define GEMM_TILE(CUR, WAIT, PRE, KK2)                                        \
  {                                                                           \
    WAIT; SBAR; SCHED0;                                                       \
    const bf16_t* Ac = &As[CUR][0];                                           \
    const bf16_t* Bc = &Bs[CUR][0];                                           \
    bf16x8 af[4], bfr[4];                                                     \
    _Pragma("unroll") for (int i_ = 0; i_ < 4; ++i_)                          \
      af[i_] = *(const bf16x8*)(Ac + (wm + i_ * 16 + l16) * 32 + fcol);       \
    _Pragma("unroll") for (int j_ = 0; j_ < 4; ++j_)                          \
      bfr[j_] = *(const bf16x8*)(Bc + (wn + j_ * 16 + l16) * 32 + fcol);      \
    _Pragma("unroll") for (int i_ = 0; i_ < 4; ++i_)                          \
      _Pragma("unroll") for (int j_ = 0; j_ < 4; ++j_)                        \
        acc[i_][j_] = mfma_16x16x32(af[i_], bfr[j_], acc[i_][j_]);            \
    WAITL0; SBAR; SCHED0;                                                     \
    if (PRE) {                                                                \
      const int kk2_ = (KK2);                                                 \
      GLD16(Ag0 + kk2_, &As[CUR][0] + ld0);                                   \
      GLD16(Ag1 + kk2_, &As[CUR][0] + ld1);                                   \
      GLD16(Bg0 + kk2_, &Bs[CUR][0] + ld0);                                   \
      GLD16(Bg1 + kk2_, &Bs[CUR][0] + ld1);                                   \
    }                                                                         \
  }

#define GEMM_LOOP                                                             \
  GLD16(Ag0, &As[0][0] + ld0); GLD16(Ag1, &As[0][0] + ld1);                   \
  GLD16(Bg0, &Bs[0][0] + ld0); GLD16(Bg1, &Bs[0][0] + ld1);                   \
  GLD16(Ag0 + 32, &As[1][0] + ld0); GLD16(Ag1 + 32, &As[1][0] + ld1);         \
  GLD16(Bg0 + 32, &Bs[1][0] + ld0); GLD16(Bg1 + 32, &Bs[1][0] + ld1);         \
  for (int ii = 0; ii < 15; ++ii) {                                           \
    const int kk2a = ii * 64 + 64;                                            \
    GEMM_TILE(0, WAITV4, true, kk2a);                                         \
    GEMM_TILE(1, WAITV4, true, kk2a + 32);                                    \
  }                                                                           \
  GEMM_TILE(0, WAITV4, false, 0);                                             \
  GEMM_TILE(1, WAITV0, false, 0);

// ---------------------------------------------------------------------------
// Fused QKV projection (r6-proven): ONE dispatch, blockIdx.z in {0,1,2}.
// 128x128-tile bf16 GEMM; swizzled LDS (conflicts 0), 2-deep counted-vmcnt.
// RoPE epilogue reads interleaved float2 (cos,sin) table.
// ---------------------------------------------------------------------------
__global__ __launch_bounds__(256) void qkv_proj_kernel(const bf16_t* __restrict__ X,
                                                       const bf16_t* __restrict__ Wb,
                                                       const float* __restrict__ bq,
                                                       const float* __restrict__ bk,
                                                       const float* __restrict__ bv,
                                                       const float2* __restrict__ csq,
                                                       const float2* __restrict__ csk,
                                                       bf16_t* __restrict__ qtb,
                                                       bf16_t* __restrict__ ktb,
                                                       bf16_t* __restrict__ vtb) {
  __shared__ bf16_t As[2][128 * 32];
  __shared__ bf16_t Bs[2][128 * 32];
  const int z = blockIdx.z;
  const bf16_t* A  = X  + (size_t)z * TOKENS * DM;
  const bf16_t* Bw = Wb + (size_t)z * DM * DM;
  const float* bias = (z == 0) ? bq : (z == 1) ? bk : bv;

  const int tid  = threadIdx.x;
  const int wave = tid >> 6, lane = tid & 63;
  const int quad = lane >> 4, l16 = lane & 15;
  const int m0 = blockIdx.x * 128, n0 = blockIdx.y * 128;
  const int wm = (wave >> 1) * 64, wn = (wave & 1) * 64;

  f32x4 acc[4][4];
#pragma unroll
  for (int i = 0; i < 4; ++i)
#pragma unroll
    for (int j = 0; j < 4; ++j) acc[i][j] = (f32x4){0.f, 0.f, 0.f, 0.f};

  // staging: lane covers LDS (row = c*16 + lane>>2, blk = lane&3); source
  // col-block pre-swizzled so LDS (row,blk) holds global blk^((row>>1)&3)
  const int srow = lane >> 2;
  const int scol = ((lane & 3) ^ ((lane >> 3) & 3)) * 8;
  const int c0 = wave * 2, c1 = c0 + 1;
  const int r0 = c0 * 16 + srow, r1 = c1 * 16 + srow;
  const bf16_t* Ag0 = A  + (size_t)(m0 + r0) * DM + scol;
  const bf16_t* Ag1 = A  + (size_t)(m0 + r1) * DM + scol;
  const bf16_t* Bg0 = Bw + (size_t)(n0 + r0) * DM + scol;
  const bf16_t* Bg1 = Bw + (size_t)(n0 + r1) * DM + scol;
  const int ld0 = c0 * 512, ld1 = c1 * 512;

  // fragment reads: XOR by (l16>>1)&3 (row = wm/wn + i*16 + l16; wm,16i == 0 mod 8)
  const int fcol = ((quad ^ ((l16 >> 1) & 3)) << 3);

  GEMM_LOOP

  // epilogue: C row = quad*4+reg, col = l16 (m89-verified C/D layout)
  if (z < 2) {
    const float2* cst = (z == 0) ? csq : csk;
    bf16_t* out = (z == 0) ? qtb : ktb;
    const int h = (n0 + wn) >> 6;
#pragma unroll
    for (int i = 0; i < 4; ++i) {
#pragma unroll
      for (int j = 0; j < 2; ++j) {
        const int hd1 = j * 16 + l16;
        const int hd2 = hd1 + 32;
        const float bn1 = bias[n0 + wn + hd1];
        const float bn2 = bias[n0 + wn + hd2];
#pragma unroll
        for (int r = 0; r < 4; ++r) {
          const int m = m0 + wm + i * 16 + quad * 4 + r;
          const int b = m >> 11, l = m & (LSEQ - 1);
          const size_t cb = ((size_t)b * LSEQ + l) * HD;
          // explicit bf16 round BEFORE rope (verified numerics)
          const float x1 = (float)(bf16_t)(acc[i][j][r] + bn1);
          const float x2 = (float)(bf16_t)(acc[i][j + 2][r] + bn2);
          const float2 cs1 = cst[cb + hd1];
          const float2 cs2 = cst[cb + hd2];
          bf16_t* dst = out + (((size_t)(b * NH + h)) * LSEQ + l) * HD;
          dst[hd1] = (bf16_t)(x1 * cs1.x - x2 * cs1.y);
          dst[hd2] = (bf16_t)(x2 * cs2.x + x1 * cs2.y);
        }
      }
    }
  } else {
#pragma unroll
    for (int i = 0; i < 4; ++i) {
      const int mb = m0 + wm + i * 16 + quad * 4;
      const int b = mb >> 11, l = mb & (LSEQ - 1);
#pragma unroll
      for (int j = 0; j < 4; ++j) {
        const int n = n0 + wn + j * 16 + l16;
        const int h = n >> 6, hd = n & (HD - 1);
        const float bn = bias[n];
        bf16x4 pk;
#pragma unroll
        for (int r = 0; r < 4; ++r) pk[r] = (bf16_t)(acc[i][j][r] + bn);
        *(bf16x4*)(vtb + (((size_t)(b * NH + h)) * HD + hd) * LSEQ + l) = pk;
      }
    }
  }
}

// ---------------------------------------------------------------------------
// Out projection: C = A * Wo^T + bo, f32 store (r6-proven config)
// ---------------------------------------------------------------------------
__global__ __launch_bounds__(256) void out_gemm_kernel(const bf16_t* __restrict__ A,
                                                       const bf16_t* __restrict__ Bw,
                                                       const float* __restrict__ bias,
                                                       float* __restrict__ out) {
  __shared__ bf16_t As[2][128 * 32];
  __shared__ bf16_t Bs[2][128 * 32];
  const int tid  = threadIdx.x;
  const int wave = tid >> 6, lane = tid & 63;
  const int quad = lane >> 4, l16 = lane & 15;
  const int m0 = blockIdx.x * 128, n0 = blockIdx.y * 128;
  const int wm = (wave >> 1) * 64, wn = (wave & 1) * 64;

  f32x4 acc[4][4];
#pragma unroll
  for (int i = 0; i < 4; ++i)
#pragma unroll
    for (int j = 0; j < 4; ++j) acc[i][j] = (f32x4){0.f, 0.f, 0.f, 0.f};

  const int srow = lane >> 2;
  const int scol = ((lane & 3) ^ ((lane >> 3) & 3)) * 8;
  const int c0 = wave * 2, c1 = c0 + 1;
  const int r0 = c0 * 16 + srow, r1 = c1 * 16 + srow;
  const bf16_t* Ag0 = A  + (size_t)(m0 + r0) * DM + scol;
  const bf16_t* Ag1 = A  + (size_t)(m0 + r1) * DM + scol;
  const bf16_t* Bg0 = Bw + (size_t)(n0 + r0) * DM + scol;
  const bf16_t* Bg1 = Bw + (size_t)(n0 + r1) * DM + scol;
  const int ld0 = c0 * 512, ld1 = c1 * 512;
  const int fcol = ((quad ^ ((l16 >> 1) & 3)) << 3);

  GEMM_LOOP

#pragma unroll
  for (int i = 0; i < 4; ++i)
#pragma unroll
    for (int j = 0; j < 4; ++j) {
      const int n  = n0 + wn + j * 16 + l16;
      const float bn = bias[n];
#pragma unroll
      for (int r = 0; r < 4; ++r) {
        const int m = m0 + wm + i * 16 + quad * 4 + r;
        out[(size_t)m * DM + n] = acc[i][j][r] + bn;
      }
    }
}

// ---------------------------------------------------------------------------
// Flash attention v8: QBLK 128 -> 256 (8 waves, 512 threads). Rationale:
// FETCH 139MB ~= 3x compulsory K/V (16 q-blocks/head each re-stage 512KB);
// doubling q-rows/block halves that. The per-tile sync template is UNCHANGED
// (parameter inheritance): per-wave loads/tile 4 -> 2, so counted waits are
// vmcnt(2) (prologue 4, tail 2/0); each wave still owns 32 q-rows so all
// fragment math, P transpose, ones-MFMA, epilogue are verbatim v7.
// Occupancy identical: 512 blocks = 2/CU x 8 waves = 16 waves/CU.
// ---------------------------------------------------------------------------
#define ATTN_TILE(K0)                                                         \
  {                                                                           \
    const bf16_t* Kc = &Kl[cur][0];                                           \
    const bf16_t* Vc = &Vl[cur][0];                                           \
    f32x4 S[2][4];                                                            \
    _Pragma("unroll") for (int j = 0; j < 4; ++j) {                           \
      const bf16x8 kb0 = *(const bf16x8*)(Kc + oA + j * 1024);                \
      const bf16x8 kb1 = *(const bf16x8*)(Kc + oB + j * 1024);                \
      _Pragma("unroll") for (int u = 0; u < 2; ++u) {                         \
        f32x4 a = (f32x4){0.f, 0.f, 0.f, 0.f};                                \
        a = mfma_16x16x32(kb0, qa[u][0], a);                                  \
        a = mfma_16x16x32(kb1, qa[u][1], a);                                  \
        _Pragma("unroll") for (int r = 0; r < 4; ++r)                         \
          S[u][j][r] = __builtin_amdgcn_exp2f(a[r] * scale_l2e);              \
      }                                                                       \
    }                                                                         \
    if (has_mask) {                                                           \
      const uint64_t mlo = *(const uint64_t*)(mrow + (K0) + quad * 8);        \
      const uint64_t mhi = *(const uint64_t*)(mrow + (K0) + 32 + quad * 8);   \
      if (!__all((mlo | mhi) == 0)) {                                         \
        _Pragma("unroll") for (int j = 0; j < 4; ++j) {                       \
          const uint64_t mm = (j & 2) ? mhi : mlo;                            \
          _Pragma("unroll") for (int r = 0; r < 4; ++r)                       \
            if ((mm >> (((j & 1) * 4 + r) * 8)) & 0xff) {                     \
              S[0][j][r] = 0.f;                                               \
              S[1][j][r] = 0.f;                                               \
            }                                                                 \
        }                                                                     \
      }                                                                       \
    }                                                                         \
    bf16x8 pa[2][2];                                                          \
    _Pragma("unroll") for (int u = 0; u < 2; ++u)                             \
      _Pragma("unroll") for (int f = 0; f < 2; ++f)                           \
        _Pragma("unroll") for (int e = 0; e < 8; ++e)                         \
          pa[u][f][e] = (bf16_t)S[u][2 * f + (e >> 2)][e & 3];                \
    _Pragma("unroll") for (int u = 0; u < 2; ++u) {                           \
      Ol[u] = mfma_16x16x32(pa[u][0], ones, Ol[u]);                           \
      Ol[u] = mfma_16x16x32(pa[u][1], ones, Ol[u]);                           \
    }                                                                         \
    _Pragma("unroll") for (int jd = 0; jd < 4; ++jd) {                        \
      const bf16x8 vb0 = *(const bf16x8*)(Vc + oA + jd * 1024);               \
      const bf16x8 vb1 = *(const bf16x8*)(Vc + oB + jd * 1024);               \
      _Pragma("unroll") for (int u = 0; u < 2; ++u) {                         \
        O[u][jd] = mfma_16x16x32(pa[u][0], vb0, O[u][jd]);                    \
        O[u][jd] = mfma_16x16x32(pa[u][1], vb1, O[u][jd]);                    \
      }                                                                       \
    }                                                                         \
  }

__global__ __launch_bounds__(512, 4) void attn_kernel(const bf16_t* __restrict__ qt,
                                                      const bf16_t* __restrict__ kt,
                                                      const bf16_t* __restrict__ vt,
                                                      const unsigned char* __restrict__ mask,
                                                      bf16_t* __restrict__ ctx) {
  __shared__ bf16_t Kl[2][64 * 64];        // [pos][d], col-blocks swizzled by pos&7
  __shared__ bf16_t Vl[2][64 * 64];        // [d][kk],  col-blocks swizzled by d&7
  __shared__ int mflag;
  // XCD remap over 512 blocks (8 q-tiles x 64 bh): XCD a <- bh in [8a,8a+8)
  const int L  = blockIdx.x + (blockIdx.y << 3);
  const int bh = ((L & 7) << 3) | ((L >> 3) & 7);
  const int q0 = (L >> 6) * 256;
  const int b = bh >> 4, h = bh & (NH - 1);
  const int tid = threadIdx.x;
  const int wave = tid >> 6, lane = tid & 63;   // wave 0..7
  const int quad = lane >> 4, l16 = lane & 15;
  const float scale_l2e = 0.125f * 1.44269504f;  // HD^-0.5 * log2(e)

  const bf16_t* kbase = kt + (size_t)bh * LSEQ * HD;
  const bf16_t* vbase = vt + (size_t)bh * HD * LSEQ;
  const unsigned char* mrow = mask + (size_t)b * LSEQ;

  if (tid == 0) mflag = 0;
  __syncthreads();
  // mask pre-scan: first 256 threads x 8B = entire 2048B row
  if (tid < 256) {
    const uint64_t mw = ((const uint64_t*)mrow)[tid];
    if (mw != 0) atomicOr(&mflag, 1);
  }

  // Q fragments (m=l16, k=quad*8+e), used as B-operand of swapped QK^T;
  // each wave owns 32 q-rows: q0 + wave*32 + u*16 (identical to v7)
  bf16x8 qa[2][2];
#pragma unroll
  for (int u = 0; u < 2; ++u) {
    const bf16_t* qrow = qt + (((size_t)bh * LSEQ) + q0 + wave * 32 + u * 16 + l16) * HD;
    qa[u][0] = *(const bf16x8*)(qrow + quad * 8);
    qa[u][1] = *(const bf16x8*)(qrow + 32 + quad * 8);
  }

  f32x4 O[2][4];
  f32x4 Ol[2];
#pragma unroll
  for (int u = 0; u < 2; ++u) {
    Ol[u] = (f32x4){0.f, 0.f, 0.f, 0.f};
#pragma unroll
    for (int j = 0; j < 4; ++j) O[u][j] = (f32x4){0.f, 0.f, 0.f, 0.f};
  }
  bf16x8 ones;
#pragma unroll
  for (int e = 0; e < 8; ++e) ones[e] = (bf16_t)1.0f;

  // --- hoisted per-lane offsets: 8 waves cover 8 chunks of 8 rows each ---
  const int srow8 = lane >> 3;  // 0..7 within 8-row chunk
  const int scb   = lane & 7;   // LDS col-block position
  const int p  = wave * 8 + srow8;       // LDS row (K: position, V: d)
  const int g0 = (scb ^ srow8) * 8;      // p&7 == srow8
  const int sig = ((p >> 5) << 5) | (((p >> 2) & 3) << 3) | (((p >> 4) & 1) << 2) | (p & 3);
  const int kgo = sig * HD + g0;         // K global lane offset (sigma-permuted)
  const int vgo = p * LSEQ + g0;         // V global lane offset
  const int ld  = wave * 512;            // LDS dst offset (chunk = wave)

  // fragment-read offsets: sw = (j*16+l16)&7 == l16&7 for all j
  const int sw  = l16 & 7;
  const int oA  = l16 * 64 + ((quad ^ sw) << 3);
  const int oB  = l16 * 64 + (((quad + 4) ^ sw) << 3);

  // prologue: stage tiles 0 and 1 (2 loads/thread/tile; 4 in flight)
  GLD16(kbase + kgo, &Kl[0][0] + ld);
  GLD16(vbase + vgo, &Vl[0][0] + ld);
  GLD16(kbase + (size_t)64 * HD + kgo, &Kl[1][0] + ld);
  GLD16(vbase + (size_t)(vgo + 64), &Vl[1][0] + ld);

  // non-draining mflag sync: own atomic done (lgkm), then barrier, then read
  WAITL0; SBAR;
  const bool has_mask = (mflag != 0);

  int cur = 0;
  for (int t = 0; t < 30; ++t) {
    WAITV2; SBAR; SCHED0;
    ATTN_TILE(t * 64);
    WAITL0; SBAR; SCHED0;
    {
      const int k0n = t * 64 + 128;
      GLD16(kbase + (size_t)k0n * HD + kgo, &Kl[cur][0] + ld);
      GLD16(vbase + (size_t)(vgo + k0n), &Vl[cur][0] + ld);
    }
    cur ^= 1;
  }
  // t=30: own loads are oldest 2 of 4
  WAITV2; SBAR; SCHED0;
  ATTN_TILE(30 * 64);
  cur ^= 1;
  // t=31: last tile
  WAITV0; SBAR; SCHED0;
  ATTN_TILE(31 * 64);

  // epilogue: normalize and write ctx [B, LSEQ, NH*HD] bf16 (token-major)
#pragma unroll
  for (int u = 0; u < 2; ++u) {
    f32x4 linv;
#pragma unroll
    for (int r = 0; r < 4; ++r) linv[r] = 1.0f / Ol[u][r];
#pragma unroll
    for (int jd = 0; jd < 4; ++jd)
#pragma unroll
      for (int r = 0; r < 4; ++r) {
        const int l = q0 + wave * 32 + u * 16 + quad * 4 + r;
        const int d = h * HD + jd * 16 + l16;
        const float o = O[u][jd][r] * linv[r];
        ctx[((size_t)b * LSEQ + l) * DM + d] = (bf16_t)o;
      }
  }
}

// ---------------------------------------------------------------------------
extern "C" void kernel_launch(void* const* d_in, const int* in_sizes, int n_in,
                              void* d_out, int out_size, void* d_ws, size_t ws_size,
                              hipStream_t stream) {
  (void)in_sizes; (void)n_in; (void)out_size; (void)ws_size;
  const float* query = (const float*)d_in[0];
  const float* key   = (const float*)d_in[1];
  const float* value = (const float*)d_in[2];
  const float* cos_q = (const float*)d_in[3];
  const float* sin_q = (const float*)d_in[4];
  const float* cos_k = (const float*)d_in[5];
  const float* sin_k = (const float*)d_in[6];
  const unsigned char* mask = (const unsigned char*)d_in[7];
  const float* Wq = (const float*)d_in[8];
  const float* bq = (const float*)d_in[9];
  const float* Wk = (const float*)d_in[10];
  const float* bk = (const float*)d_in[11];
  const float* Wv = (const float*)d_in[12];
  const float* bv = (const float*)d_in[13];
  const float* Wo = (const float*)d_in[14];
  const float* bo = (const float*)d_in[15];
  float* out = (float*)d_out;

  const size_t ACT = (size_t)TOKENS * DM;  // 8388608
  const size_t WEL = (size_t)DM * DM;      // 1048576
  const size_t CSN = (size_t)TOKENS * HD;  // 524288 float2 per table

  bf16_t* p   = (bf16_t*)d_ws;
  bf16_t* xq  = p; p += ACT;    // xq,xk,xv contiguous (prep dst / qkv A base)
  bf16_t* xk  = p; p += ACT;
  bf16_t* xv  = p; p += ACT;
  bf16_t* wqb = p; p += WEL;    // wqb..wob contiguous (prep dst / qkv W base)
  bf16_t* wkb = p; p += WEL;
  bf16_t* wvb = p; p += WEL;
  bf16_t* wob = p; p += WEL;
  bf16_t* qtb = p; p += ACT;
  bf16_t* ktb = p; p += ACT;
  bf16_t* vtb = p; p += ACT;
  bf16_t* ctx = xk;  // alias: xk dead after qkv proj
  (void)xv; (void)wkb; (void)wvb;

  // cos/sin float2 tables live in d_out (32MB f32): only out_gemm writes
  // d_out, at the very end — free scratch until then.
  float2* csq = (float2*)out;        // 4MB
  float2* csk = csq + CSN;           // 4MB

  // fused prep: casts + cs-table build, ONE dispatch
  prep_kernel<<<dim3(29696), 256, 0, stream>>>(query, key, value, Wq, Wk, Wv, Wo,
                                               cos_q, sin_q, cos_k, sin_k,
                                               xq, wqb, csq);

  // fused q/k/v projections (one dispatch, z = which projection)
  qkv_proj_kernel<<<dim3(TOKENS / 128, DM / 128, 3), 256, 0, stream>>>(
      xq, wqb, bq, bk, bv, csq, csk, qtb, ktb, vtb);

  // flash attention -> ctx [B, LSEQ, DM] bf16 (QBLK=256, 8 waves)
  attn_kernel<<<dim3(LSEQ / 256, B_DIM * NH), 512, 0, stream>>>(qtb, ktb, vtb, mask, ctx);

  // output projection -> f32 d_out (overwrites the cs scratch)
  out_gemm_kernel<<<dim3(TOKENS / 128, DM / 128), 256, 0, stream>>>(ctx, wob, bo, out);
}